// Round 2
// baseline (682.902 us; speedup 1.0000x reference)
//
#include <hip/hip_runtime.h>
#include <hip/hip_bf16.h>

// Attention_50946902065218: Bahdanau-style attention
// B=256, L=196, E=2048, D=1024, A=512
// Pipeline:
//  k_wepack: We fp32 -> bf16, packed per-K-step-contiguous [kb][n][k'] (ws)
//  k_bias2 : bias2[b][a] = be[a] + bd[a] + dec[b]@Wd[:,a]                (ws)
//  k_gemm_score: scores[b*196+l] = sum_a wf[a]*tanh((enc@We)[m,a]+bias2) (ws)
//    -> v2: LDS-free, barrier-free register-pipelined MFMA loop.
//       A fragments read direct from enc (fp32->bf16 in regs, 2-step prefetch)
//       B fragments read direct from packed WeP in L2 (1-step prefetch)
//  k_softmax: mask + softmax over L -> alpha (d_out part 2)
//  k_awe   : awe[b,e] = sum_l alpha[b,l]*enc[b,l,e]  (d_out part 1)

#define B_ 256
#define L_ 196
#define E_ 2048
#define D_ 1024
#define A_ 512
#define M_TOT (B_ * L_)   // 50176 = 784 * 64

typedef __attribute__((ext_vector_type(8))) short bf16x8;
typedef __attribute__((ext_vector_type(4))) float f32x4;

static __device__ __forceinline__ unsigned short f2bf(float f) {
    union { float f; unsigned u; } u{f};
    unsigned r = u.u + 0x7fffu + ((u.u >> 16) & 1u);   // RNE
    return (unsigned short)(r >> 16);
}

// ---------------- kernel 0a: pack We (E x A fp32) -> WeP bf16 -----------------
// WeP layout: [kb][n][k'] with kb = k/32, k' = k%32
__global__ __launch_bounds__(256) void k_wepack(const float* __restrict__ We,
                                                unsigned short* __restrict__ WeP) {
    int i = blockIdx.x * 256 + threadIdx.x;       // source index over 2048*512
    int k = i >> 9, n = i & 511;
    WeP[((k >> 5) << 14) + (n << 5) + (k & 31)] = f2bf(We[i]);
}

// ---------------- kernel 0b: bias2 = be + bd + dec @ Wd ----------------------
__global__ __launch_bounds__(256) void k_bias2(const float* __restrict__ dec,
                                               const float* __restrict__ Wd,
                                               const float* __restrict__ be,
                                               const float* __restrict__ bd,
                                               float* __restrict__ bias2) {
    int b = blockIdx.x, t = threadIdx.x;
    __shared__ float ds[D_];
    for (int i = t; i < D_; i += 256) ds[i] = dec[b * D_ + i];
    __syncthreads();
    for (int a0 = 0; a0 < A_; a0 += 256) {
        int a = a0 + t;
        float acc = 0.f;
        #pragma unroll 8
        for (int d = 0; d < D_; d++) acc += ds[d] * Wd[d * A_ + a];
        bias2[b * A_ + a] = acc + be[a] + bd[a];
    }
}

// ---------------- kernel 1: fused GEMM + tanh + wf-dot -----------------------
// grid 784 blocks x 512 threads (8 waves: wm in {0,1} x wn in {0..3}).
// Per wave: 32 rows x 128 cols of the 64x512 block tile. No LDS, no barriers:
// A and B fragments stream straight into registers, software-pipelined.
__global__ __launch_bounds__(512, 3) void k_gemm_score(
        const float* __restrict__ enc,
        const unsigned short* __restrict__ WeP,
        const float* __restrict__ bias2,
        const float* __restrict__ wf,
        float* __restrict__ scores) {
    __shared__ float score_lds[64];

    const int tid = threadIdx.x;
    const int m0 = blockIdx.x * 64;
    const int lane = tid & 63;
    const int wid = tid >> 6;
    const int wm = wid >> 2, wn = wid & 3;
    const int kg = lane >> 4, lr = lane & 15;

    // A: lane holds rows (wm*32 + i*16 + lr), k = kb*32 + kg*8 + e  (8 fp32)
    const float* aP0 = enc + (size_t)(m0 + wm * 32 + lr) * E_ + kg * 8;
    const float* aP1 = aP0 + 16 * E_;
    // B: lane holds col n = wn*128 + j*16 + lr, k = kb*32 + kg*8 + e (8 bf16)
    //    WeP addr (shorts) = kb*16384 + n*32 + kg*8
    const unsigned short* bP = WeP + (wn * 128 + lr) * 32 + kg * 8;

    f32x4 acc[2][8];
    #pragma unroll
    for (int i = 0; i < 2; i++)
        #pragma unroll
        for (int j = 0; j < 8; j++) acc[i][j] = (f32x4){0.f, 0.f, 0.f, 0.f};

    float4 a0[2][2], a1[2][2];   // [i][half] fp32 prefetch regs (2-step depth)
    bf16x8 bR[8];                // current-step B fragments (1-step depth)

    // prologue: A(0)->a0, A(1)->a1, B(0)->bR
    #pragma unroll
    for (int i = 0; i < 2; i++) {
        const float* p = (i ? aP1 : aP0);
        a0[i][0] = *reinterpret_cast<const float4*>(p);
        a0[i][1] = *reinterpret_cast<const float4*>(p + 4);
        a1[i][0] = *reinterpret_cast<const float4*>(p + 32);
        a1[i][1] = *reinterpret_cast<const float4*>(p + 36);
    }
    #pragma unroll
    for (int j = 0; j < 8; j++)
        bR[j] = *reinterpret_cast<const bf16x8*>(bP + j * 512);

    // phase(aC, tc): convert+MFMA step tc from (aC, bR);
    //                prefetch A(tc+2)->aC (after conversion, WAR-safe)
    //                prefetch B(tc+1)->bR (after MFMA reads, WAR-safe)
    auto phase = [&](float4 (&aC)[2][2], int tc) {
        bf16x8 af[2];
        #pragma unroll
        for (int i = 0; i < 2; i++) {
            union { bf16x8 v; unsigned short s[8]; } u;
            u.s[0] = f2bf(aC[i][0].x); u.s[1] = f2bf(aC[i][0].y);
            u.s[2] = f2bf(aC[i][0].z); u.s[3] = f2bf(aC[i][0].w);
            u.s[4] = f2bf(aC[i][1].x); u.s[5] = f2bf(aC[i][1].y);
            u.s[6] = f2bf(aC[i][1].z); u.s[7] = f2bf(aC[i][1].w);
            af[i] = u.v;
        }
        if (tc + 2 < 64) {
            #pragma unroll
            for (int i = 0; i < 2; i++) {
                const float* p = (i ? aP1 : aP0) + (tc + 2) * 32;
                aC[i][0] = *reinterpret_cast<const float4*>(p);
                aC[i][1] = *reinterpret_cast<const float4*>(p + 4);
            }
        }
        #pragma unroll
        for (int i = 0; i < 2; i++)
            #pragma unroll
            for (int j = 0; j < 8; j++)
                acc[i][j] = __builtin_amdgcn_mfma_f32_16x16x32_bf16(
                    af[i], bR[j], acc[i][j], 0, 0, 0);
        if (tc + 1 < 64) {
            const unsigned short* bp = bP + (size_t)(tc + 1) * 16384;
            #pragma unroll
            for (int j = 0; j < 8; j++)
                bR[j] = *reinterpret_cast<const bf16x8*>(bp + j * 512);
        }
    };

    for (int t = 0; t < 64; t += 2) {
        phase(a0, t);
        phase(a1, t + 1);
    }

    // --- epilogue: tanh + wf dot, reduce over cols ---
    if (tid < 64) score_lds[tid] = 0.f;
    __syncthreads();
    #pragma unroll
    for (int i = 0; i < 2; i++) {
        #pragma unroll
        for (int r = 0; r < 4; r++) {
            int R = wm * 32 + i * 16 + kg * 4 + r;   // C/D: col=lane&15, row=(lane>>4)*4+reg
            int gm = m0 + R;
            int bg = gm / L_;
            float sum = 0.f;
            #pragma unroll
            for (int j = 0; j < 8; j++) {
                int C = wn * 128 + j * 16 + lr;
                float x = acc[i][j][r] + bias2[bg * A_ + C];
                // fast tanh: 1 - 2/(e^{2x}+1)  (saturates correctly at +-inf)
                float ex = __expf(2.f * x);
                float th = 1.f - 2.f * __builtin_amdgcn_rcpf(ex + 1.f);
                sum += wf[C] * th;
            }
            #pragma unroll
            for (int mk = 1; mk < 16; mk <<= 1) sum += __shfl_xor(sum, mk);
            if (lr == 0) atomicAdd(&score_lds[R], sum);
        }
    }
    __syncthreads();
    if (tid < 64) scores[m0 + tid] = score_lds[tid];
}

// ---------------- kernel 2: mask + softmax over L ----------------------------
__global__ __launch_bounds__(256) void k_softmax(const float* __restrict__ scores,
                                                 const int* __restrict__ mask,
                                                 const float* __restrict__ bfp,
                                                 float* __restrict__ alpha) {
    int b = blockIdx.x, t = threadIdx.x;
    float bfv = bfp[0];
    float v = -INFINITY;
    if (t < L_) v = (mask[b * L_ + t] == 0) ? -1e9f : (scores[b * L_ + t] + bfv);
    __shared__ float redm[4], reds[4];
    float m = v;
    #pragma unroll
    for (int s = 1; s < 64; s <<= 1) m = fmaxf(m, __shfl_xor(m, s));
    int w = t >> 6;
    if ((t & 63) == 0) redm[w] = m;
    __syncthreads();
    m = fmaxf(fmaxf(redm[0], redm[1]), fmaxf(redm[2], redm[3]));
    float e = (t < L_) ? expf(v - m) : 0.f;
    float s = e;
    #pragma unroll
    for (int k = 1; k < 64; k <<= 1) s += __shfl_xor(s, k);
    if ((t & 63) == 0) reds[w] = s;
    __syncthreads();
    s = reds[0] + reds[1] + reds[2] + reds[3];
    if (t < L_) alpha[b * L_ + t] = e / s;
}

// ---------------- kernel 3: awe = sum_l alpha * enc --------------------------
// grid (8 e-chunks of 256, 256 batches), 64 threads, 1 float4/thread
__global__ __launch_bounds__(64) void k_awe(const float* __restrict__ enc,
                                            const float* __restrict__ alpha,
                                            float* __restrict__ awe) {
    int b = blockIdx.y, ec = blockIdx.x, t = threadIdx.x;
    __shared__ float al[L_];
    for (int l = t; l < L_; l += 64) al[l] = alpha[b * L_ + l];
    __syncthreads();
    int e0 = (ec << 8) + (t << 2);
    const float* base = enc + (size_t)b * L_ * E_ + e0;
    float4 acc = {0.f, 0.f, 0.f, 0.f};
    #pragma unroll 4
    for (int l = 0; l < L_; l++) {
        float4 v = *reinterpret_cast<const float4*>(base + (size_t)l * E_);
        float a = al[l];
        acc.x += a * v.x; acc.y += a * v.y; acc.z += a * v.z; acc.w += a * v.w;
    }
    *reinterpret_cast<float4*>(awe + b * E_ + e0) = acc;
}

extern "C" void kernel_launch(void* const* d_in, const int* in_sizes, int n_in,
                              void* d_out, int out_size, void* d_ws, size_t ws_size,
                              hipStream_t stream) {
    const float* enc  = (const float*)d_in[0];
    const float* dec  = (const float*)d_in[1];
    const int*   mask = (const int*)d_in[2];
    const float* We   = (const float*)d_in[3];
    const float* be   = (const float*)d_in[4];
    const float* Wd   = (const float*)d_in[5];
    const float* bd   = (const float*)d_in[6];
    const float* wf   = (const float*)d_in[7];
    const float* bf   = (const float*)d_in[8];

    float* awe   = (float*)d_out;                  // [256][2048]
    float* alpha = awe + (size_t)B_ * E_;          // [256][196]

    char* ws = (char*)d_ws;
    unsigned short* WeP = (unsigned short*)ws;                       // 2 MB
    float* bias2  = (float*)(ws + (2u << 20));                       // 512 KB
    float* scores = (float*)(ws + (2u << 20) + (512u << 10));        // 200 KB

    hipLaunchKernelGGL(k_wepack, dim3((E_ * A_) / 256), dim3(256), 0, stream, We, WeP);
    hipLaunchKernelGGL(k_bias2, dim3(B_), dim3(256), 0, stream, dec, Wd, be, bd, bias2);
    hipLaunchKernelGGL(k_gemm_score, dim3(M_TOT / 64), dim3(512), 0, stream,
                       enc, WeP, bias2, wf, scores);
    hipLaunchKernelGGL(k_softmax, dim3(B_), dim3(256), 0, stream, scores, mask, bf, alpha);
    hipLaunchKernelGGL(k_awe, dim3(8, B_), dim3(64), 0, stream, enc, alpha, awe);
}

// Round 3
// 491.507 us; speedup vs baseline: 1.3894x; 1.3894x over previous
//
#include <hip/hip_runtime.h>
#include <hip/hip_bf16.h>

// Attention_50946902065218: Bahdanau-style attention
// B=256, L=196, E=2048, D=1024, A=512
// Pipeline:
//  k_wepack: We fp32 -> bf16, packed per-K-step-contiguous [kb][n][k'] (ws)
//  k_bias2 : bias2[b][a] = be[a] + bd[a] + dec[b]@Wd[:,a]                (ws)
//  k_gemm_score (v3): 2-phase LDS double-buffered MFMA GEMM.
//     B staged via global_load_lds (linear 32KB slices, L2-resident WeP)
//     A reg-staged fp32->bf16, value pipelined one iteration ahead
//  k_softmax: mask + softmax over L -> alpha (d_out part 2)
//  k_awe (v2): 4-way L-split reduction, 256-thread blocks

#define B_ 256
#define L_ 196
#define E_ 2048
#define D_ 1024
#define A_ 512
#define M_TOT (B_ * L_)   // 50176 = 784 * 64

typedef __attribute__((ext_vector_type(8))) short bf16x8;
typedef __attribute__((ext_vector_type(4))) float f32x4;

static __device__ __forceinline__ unsigned short f2bf(float f) {
    union { float f; unsigned u; } u{f};
    unsigned r = u.u + 0x7fffu + ((u.u >> 16) & 1u);   // RNE
    return (unsigned short)(r >> 16);
}

static __device__ __forceinline__ void gload_lds16(const void* g, void* l) {
    __builtin_amdgcn_global_load_lds(
        (const __attribute__((address_space(1))) unsigned int*)g,
        (__attribute__((address_space(3))) unsigned int*)l, 16, 0, 0);
}

// ---------------- kernel 0a: pack We (E x A fp32) -> WeP bf16 -----------------
// WeP layout: [kb][n][k'] with kb = k/32, k' = k%32  (k-step slices contiguous)
__global__ __launch_bounds__(256) void k_wepack(const float* __restrict__ We,
                                                unsigned short* __restrict__ WeP) {
    int i = blockIdx.x * 256 + threadIdx.x;       // source index over 2048*512
    int k = i >> 9, n = i & 511;
    WeP[((k >> 5) << 14) + (n << 5) + (k & 31)] = f2bf(We[i]);
}

// ---------------- kernel 0b: bias2 = be + bd + dec @ Wd ----------------------
__global__ __launch_bounds__(256) void k_bias2(const float* __restrict__ dec,
                                               const float* __restrict__ Wd,
                                               const float* __restrict__ be,
                                               const float* __restrict__ bd,
                                               float* __restrict__ bias2) {
    int b = blockIdx.x, t = threadIdx.x;
    __shared__ float ds[D_];
    for (int i = t; i < D_; i += 256) ds[i] = dec[b * D_ + i];
    __syncthreads();
    for (int a0 = 0; a0 < A_; a0 += 256) {
        int a = a0 + t;
        float acc = 0.f;
        #pragma unroll 8
        for (int d = 0; d < D_; d++) acc += ds[d] * Wd[d * A_ + a];
        bias2[b * A_ + a] = acc + be[a] + bd[a];
    }
}

// ---------------- kernel 1: fused GEMM + tanh + wf-dot -----------------------
// grid 784 blocks x 512 threads (8 waves: wm in {0,1} x wn in {0..3}).
// Tile 64 rows x 512 cols, BK=32. 2-phase double-buffered LDS pipeline.
__global__ __launch_bounds__(512) void k_gemm_score(
        const float* __restrict__ enc,
        const unsigned short* __restrict__ WeP,
        const float* __restrict__ bias2,
        const float* __restrict__ wf,
        float* __restrict__ scores) {
    __shared__ __align__(16) unsigned short aL[2][64 * 32];   // 4 KB each
    __shared__ __align__(16) unsigned short bL[2][512 * 32];  // 32 KB each
    __shared__ float score_lds[64];

    const int tid = threadIdx.x;
    const int m0 = blockIdx.x * 64;
    const int lane = tid & 63;
    const int wid = tid >> 6;
    const int wm = wid >> 2, wn = wid & 3;
    const int kg = lane >> 4, lr = lane & 15;

    // A staging: thread -> row ar, 4 fp32 at col ak
    const int ar = tid >> 3, ak = (tid & 7) << 2;
    const float* aSrc = enc + (size_t)(m0 + ar) * E_ + ak;
    unsigned short* aDst[2] = { &aL[0][ar * 32 + ak], &aL[1][ar * 32 + ak] };

    // B staging: 4 x global_load_lds per wave, linear copy of 32KB K-slice
    const unsigned short* bSrcLane = WeP + (size_t)(wid * 512 + lane * 8);

    auto stageB = [&](int kb, int buf) {
        const unsigned short* s = bSrcLane + ((size_t)kb << 14);
        unsigned short* d = &bL[buf][wid * 512];
        #pragma unroll
        for (int i = 0; i < 4; i++)
            gload_lds16(s + i * 4096, d + i * 4096);
    };
    auto writeA = [&](const float4& v, int buf) {
        short4 p;
        p.x = (short)f2bf(v.x); p.y = (short)f2bf(v.y);
        p.z = (short)f2bf(v.z); p.w = (short)f2bf(v.w);
        *reinterpret_cast<short4*>(aDst[buf]) = p;
    };

    f32x4 acc[2][8];
    #pragma unroll
    for (int i = 0; i < 2; i++)
        #pragma unroll
        for (int j = 0; j < 8; j++) acc[i][j] = (f32x4){0.f, 0.f, 0.f, 0.f};

    auto computeTile = [&](int buf) {
        bf16x8 afr[2];
        #pragma unroll
        for (int i = 0; i < 2; i++)
            afr[i] = *reinterpret_cast<const bf16x8*>(
                &aL[buf][(wm * 32 + i * 16 + lr) * 32 + kg * 8]);
        bf16x8 bfr[8];
        #pragma unroll
        for (int j = 0; j < 8; j++)
            bfr[j] = *reinterpret_cast<const bf16x8*>(
                &bL[buf][(wn * 128 + j * 16 + lr) * 32 + kg * 8]);
        #pragma unroll
        for (int i = 0; i < 2; i++)
            #pragma unroll
            for (int j = 0; j < 8; j++)
                acc[i][j] = __builtin_amdgcn_mfma_f32_16x16x32_bf16(
                    afr[i], bfr[j], acc[i][j], 0, 0, 0);
    };

    // --- prologue: stage tile 0, pre-load A(1) value ---
    stageB(0, 0);
    float4 avCur = *reinterpret_cast<const float4*>(aSrc);           // A(0)
    float4 avHold = *reinterpret_cast<const float4*>(aSrc + 32);     // A(1)
    writeA(avCur, 0);
    __syncthreads();    // drains vmcnt(0): B(0) in LDS, avHold resident

    int buf = 0;
    for (int t = 0; t < 63; t++) {
        // issue next-next A load + next B stage, then compute current
        float4 avNext = avHold;
        if (t + 2 < 64)
            avNext = *reinterpret_cast<const float4*>(aSrc + (t + 2) * 32);
        stageB(t + 1, buf ^ 1);
        computeTile(buf);
        writeA(avHold, buf ^ 1);     // value already resident, no wait
        __syncthreads();             // drains vmcnt -> B(t+1), avNext complete
        avHold = avNext;
        buf ^= 1;
    }
    computeTile(buf);

    // --- epilogue: tanh + wf dot, reduce over cols ---
    if (tid < 64) score_lds[tid] = 0.f;
    __syncthreads();
    #pragma unroll
    for (int i = 0; i < 2; i++) {
        #pragma unroll
        for (int r = 0; r < 4; r++) {
            int R = wm * 32 + i * 16 + kg * 4 + r;   // C/D: col=lane&15, row=(lane>>4)*4+reg
            int gm = m0 + R;
            int bg = gm / L_;
            float sum = 0.f;
            #pragma unroll
            for (int j = 0; j < 8; j++) {
                int C = wn * 128 + j * 16 + lr;
                float x = acc[i][j][r] + bias2[bg * A_ + C];
                // fast tanh: 1 - 2/(e^{2x}+1)  (saturates correctly at +-inf)
                float ex = __expf(2.f * x);
                float th = 1.f - 2.f * __builtin_amdgcn_rcpf(ex + 1.f);
                sum += wf[C] * th;
            }
            #pragma unroll
            for (int mk = 1; mk < 16; mk <<= 1) sum += __shfl_xor(sum, mk);
            if (lr == 0) atomicAdd(&score_lds[R], sum);
        }
    }
    __syncthreads();
    if (tid < 64) scores[m0 + tid] = score_lds[tid];
}

// ---------------- kernel 2: mask + softmax over L ----------------------------
__global__ __launch_bounds__(256) void k_softmax(const float* __restrict__ scores,
                                                 const int* __restrict__ mask,
                                                 const float* __restrict__ bfp,
                                                 float* __restrict__ alpha) {
    int b = blockIdx.x, t = threadIdx.x;
    float bfv = bfp[0];
    float v = -INFINITY;
    if (t < L_) v = (mask[b * L_ + t] == 0) ? -1e9f : (scores[b * L_ + t] + bfv);
    __shared__ float redm[4], reds[4];
    float m = v;
    #pragma unroll
    for (int s = 1; s < 64; s <<= 1) m = fmaxf(m, __shfl_xor(m, s));
    int w = t >> 6;
    if ((t & 63) == 0) redm[w] = m;
    __syncthreads();
    m = fmaxf(fmaxf(redm[0], redm[1]), fmaxf(redm[2], redm[3]));
    float e = (t < L_) ? expf(v - m) : 0.f;
    float s = e;
    #pragma unroll
    for (int k = 1; k < 64; k <<= 1) s += __shfl_xor(s, k);
    if ((t & 63) == 0) reds[w] = s;
    __syncthreads();
    s = reds[0] + reds[1] + reds[2] + reds[3];
    if (t < L_) alpha[b * L_ + t] = e / s;
}

// ---------------- kernel 3: awe = sum_l alpha * enc --------------------------
// grid (8 e-chunks of 256, 256 batches), 256 threads = 4 groups x 64 lanes.
// Group g sums l in [g*49,(g+1)*49); cross-group reduce in LDS.
__global__ __launch_bounds__(256) void k_awe(const float* __restrict__ enc,
                                             const float* __restrict__ alpha,
                                             float* __restrict__ awe) {
    int b = blockIdx.y, ec = blockIdx.x, t = threadIdx.x;
    int g = t >> 6, lt = t & 63;
    __shared__ float al[L_];
    __shared__ float4 red[256];
    if (t < L_) al[t] = alpha[b * L_ + t];
    __syncthreads();
    int e0 = (ec << 8) + (lt << 2);
    const float* base = enc + (size_t)b * L_ * E_ + e0;
    float4 acc = {0.f, 0.f, 0.f, 0.f};
    int l0 = g * 49;
    #pragma unroll 7
    for (int l = l0; l < l0 + 49; l++) {
        float4 v = *reinterpret_cast<const float4*>(base + (size_t)l * E_);
        float a = al[l];
        acc.x += a * v.x; acc.y += a * v.y; acc.z += a * v.z; acc.w += a * v.w;
    }
    red[t] = acc;
    __syncthreads();
    if (t < 64) {
        float4 r0 = red[t], r1 = red[64 + t], r2 = red[128 + t], r3 = red[192 + t];
        float4 o;
        o.x = r0.x + r1.x + r2.x + r3.x;
        o.y = r0.y + r1.y + r2.y + r3.y;
        o.z = r0.z + r1.z + r2.z + r3.z;
        o.w = r0.w + r1.w + r2.w + r3.w;
        *reinterpret_cast<float4*>(awe + b * E_ + (ec << 8) + (t << 2)) = o;
    }
}

extern "C" void kernel_launch(void* const* d_in, const int* in_sizes, int n_in,
                              void* d_out, int out_size, void* d_ws, size_t ws_size,
                              hipStream_t stream) {
    const float* enc  = (const float*)d_in[0];
    const float* dec  = (const float*)d_in[1];
    const int*   mask = (const int*)d_in[2];
    const float* We   = (const float*)d_in[3];
    const float* be   = (const float*)d_in[4];
    const float* Wd   = (const float*)d_in[5];
    const float* bd   = (const float*)d_in[6];
    const float* wf   = (const float*)d_in[7];
    const float* bf   = (const float*)d_in[8];

    float* awe   = (float*)d_out;                  // [256][2048]
    float* alpha = awe + (size_t)B_ * E_;          // [256][196]

    char* ws = (char*)d_ws;
    unsigned short* WeP = (unsigned short*)ws;                       // 2 MB
    float* bias2  = (float*)(ws + (2u << 20));                       // 512 KB
    float* scores = (float*)(ws + (2u << 20) + (512u << 10));        // 200 KB

    hipLaunchKernelGGL(k_wepack, dim3((E_ * A_) / 256), dim3(256), 0, stream, We, WeP);
    hipLaunchKernelGGL(k_bias2, dim3(B_), dim3(256), 0, stream, dec, Wd, be, bd, bias2);
    hipLaunchKernelGGL(k_gemm_score, dim3(M_TOT / 64), dim3(512), 0, stream,
                       enc, WeP, bias2, wf, scores);
    hipLaunchKernelGGL(k_softmax, dim3(B_), dim3(256), 0, stream, scores, mask, bf, alpha);
    hipLaunchKernelGGL(k_awe, dim3(8, B_), dim3(256), 0, stream, enc, alpha, awe);
}

// Round 4
// 486.620 us; speedup vs baseline: 1.4034x; 1.0100x over previous
//
#include <hip/hip_runtime.h>
#include <hip/hip_bf16.h>

// Attention_50946902065218: Bahdanau-style attention
// B=256, L=196, E=2048, D=1024, A=512
// Pipeline:
//  k_wepack: We fp32 -> bf16, packed [kb][n][kg^swz(n)][e] (swizzle BAKED IN so
//            the linear global_load_lds copy lands bank-conflict-free)
//  k_bias2 : bias2[b][a] = be[a] + bd[a] + dec[b]@Wd[:,a]                (ws)
//  k_gemm_score (v4): 2-phase LDS double-buffered MFMA GEMM, XOR-swizzled
//     LDS tiles (conflict-free ds_read_b128), B via global_load_lds width-16,
//     A reg-staged fp32->bf16 with swizzled ds_write
//  k_softmax: mask + softmax over L -> alpha (d_out part 2)
//  k_awe   : 4-way L-split reduction, 256-thread blocks

#define B_ 256
#define L_ 196
#define E_ 2048
#define D_ 1024
#define A_ 512
#define M_TOT (B_ * L_)   // 50176 = 784 * 64

typedef __attribute__((ext_vector_type(8))) short bf16x8;
typedef __attribute__((ext_vector_type(4))) float f32x4;

static __device__ __forceinline__ unsigned short f2bf(float f) {
    union { float f; unsigned u; } u{f};
    unsigned r = u.u + 0x7fffu + ((u.u >> 16) & 1u);   // RNE
    return (unsigned short)(r >> 16);
}

static __device__ __forceinline__ void gload_lds16(const void* g, void* l) {
    __builtin_amdgcn_global_load_lds(
        (const __attribute__((address_space(1))) unsigned int*)g,
        (__attribute__((address_space(3))) unsigned int*)l, 16, 0, 0);
}

// ---------------- kernel 0a: pack We (E x A fp32) -> WeP bf16 -----------------
// Element (k, n): kb=k>>5, kg=(k>>3)&3, e=k&7.
// Stored at kb*16384 + n*32 + (kg ^ ((n>>1)&3))*8 + e   (swizzled 16B slots)
// => for a fragment read (16 lanes, n=base+lr, fixed kg), the 16B slot index
//    (4n + kg^((n>>1)&3)) mod 8 covers all 8 slots -> 2 lanes/bank (free).
__global__ __launch_bounds__(256) void k_wepack(const float* __restrict__ We,
                                                unsigned short* __restrict__ WeP) {
    int i = blockIdx.x * 256 + threadIdx.x;       // source index over 2048*512
    int k = i >> 9, n = i & 511;
    int kb = k >> 5, kg = (k >> 3) & 3, e = k & 7;
    int kgE = kg ^ ((n >> 1) & 3);
    WeP[(kb << 14) + (n << 5) + (kgE << 3) + e] = f2bf(We[i]);
}

// ---------------- kernel 0b: bias2 = be + bd + dec @ Wd ----------------------
__global__ __launch_bounds__(256) void k_bias2(const float* __restrict__ dec,
                                               const float* __restrict__ Wd,
                                               const float* __restrict__ be,
                                               const float* __restrict__ bd,
                                               float* __restrict__ bias2) {
    int b = blockIdx.x, t = threadIdx.x;
    __shared__ float ds[D_];
    for (int i = t; i < D_; i += 256) ds[i] = dec[b * D_ + i];
    __syncthreads();
    for (int a0 = 0; a0 < A_; a0 += 256) {
        int a = a0 + t;
        float acc = 0.f;
        #pragma unroll 8
        for (int d = 0; d < D_; d++) acc += ds[d] * Wd[d * A_ + a];
        bias2[b * A_ + a] = acc + be[a] + bd[a];
    }
}

// ---------------- kernel 1: fused GEMM + tanh + wf-dot -----------------------
// grid 784 blocks x 512 threads (8 waves: wm in {0,1} x wn in {0..3}).
// Tile 64 rows x 512 cols, BK=32. 2-phase double-buffered LDS pipeline.
__global__ __launch_bounds__(512) void k_gemm_score(
        const float* __restrict__ enc,
        const unsigned short* __restrict__ WeP,
        const float* __restrict__ bias2,
        const float* __restrict__ wf,
        float* __restrict__ scores) {
    __shared__ __align__(16) unsigned short aL[2][64 * 32];   // 4 KB each
    __shared__ __align__(16) unsigned short bL[2][512 * 32];  // 32 KB each
    __shared__ float score_lds[64];

    const int tid = threadIdx.x;
    const int m0 = blockIdx.x * 64;
    const int lane = tid & 63;
    const int wid = tid >> 6;
    const int wm = wid >> 2, wn = wid & 3;
    const int kg = lane >> 4, lr = lane & 15;

    // A staging: thread -> row ar, 4 fp32 at col ak; swizzled 16B-slot dest
    const int ar = tid >> 3, ak = (tid & 7) << 2;
    const float* aSrc = enc + (size_t)(m0 + ar) * E_ + ak;
    const int aoff = ar * 32 + (ak ^ (((ar >> 1) & 3) << 3));
    unsigned short* aDst[2] = { &aL[0][aoff], &aL[1][aoff] };

    // B staging: 4 x global_load_lds per wave, linear copy of 32KB K-slice
    // (source data pre-swizzled by k_wepack)
    const unsigned short* bSrcLane = WeP + (size_t)(wid * 512 + lane * 8);

    auto stageB = [&](int kb, int buf) {
        const unsigned short* s = bSrcLane + ((size_t)kb << 14);
        unsigned short* d = &bL[buf][wid * 512];
        #pragma unroll
        for (int i = 0; i < 4; i++)
            gload_lds16(s + i * 4096, d + i * 4096);
    };
    auto writeA = [&](const float4& v, int buf) {
        short4 p;
        p.x = (short)f2bf(v.x); p.y = (short)f2bf(v.y);
        p.z = (short)f2bf(v.z); p.w = (short)f2bf(v.w);
        *reinterpret_cast<short4*>(aDst[buf]) = p;
    };

    f32x4 acc[2][8];
    #pragma unroll
    for (int i = 0; i < 2; i++)
        #pragma unroll
        for (int j = 0; j < 8; j++) acc[i][j] = (f32x4){0.f, 0.f, 0.f, 0.f};

    auto computeTile = [&](int buf) {
        bf16x8 afr[2];
        #pragma unroll
        for (int i = 0; i < 2; i++) {
            int row = wm * 32 + i * 16 + lr;
            afr[i] = *reinterpret_cast<const bf16x8*>(
                &aL[buf][row * 32 + ((kg ^ ((row >> 1) & 3)) << 3)]);
        }
        bf16x8 bfr[8];
        #pragma unroll
        for (int j = 0; j < 8; j++) {
            int n = wn * 128 + j * 16 + lr;
            bfr[j] = *reinterpret_cast<const bf16x8*>(
                &bL[buf][n * 32 + ((kg ^ ((n >> 1) & 3)) << 3)]);
        }
        #pragma unroll
        for (int i = 0; i < 2; i++)
            #pragma unroll
            for (int j = 0; j < 8; j++)
                acc[i][j] = __builtin_amdgcn_mfma_f32_16x16x32_bf16(
                    afr[i], bfr[j], acc[i][j], 0, 0, 0);
    };

    // --- prologue: stage tile 0, pre-load A(1) value ---
    stageB(0, 0);
    float4 avCur = *reinterpret_cast<const float4*>(aSrc);           // A(0)
    float4 avHold = *reinterpret_cast<const float4*>(aSrc + 32);     // A(1)
    writeA(avCur, 0);
    __syncthreads();    // drains vmcnt(0): B(0) in LDS, avHold resident

    int buf = 0;
    for (int t = 0; t < 63; t++) {
        // issue next-next A load + next B stage, then compute current
        float4 avNext = avHold;
        if (t + 2 < 64)
            avNext = *reinterpret_cast<const float4*>(aSrc + (t + 2) * 32);
        stageB(t + 1, buf ^ 1);
        computeTile(buf);
        writeA(avHold, buf ^ 1);     // value already resident, no wait
        __syncthreads();             // drains vmcnt -> B(t+1), avNext complete
        avHold = avNext;
        buf ^= 1;
    }
    computeTile(buf);

    // --- epilogue: tanh + wf dot, reduce over cols ---
    if (tid < 64) score_lds[tid] = 0.f;
    __syncthreads();
    #pragma unroll
    for (int i = 0; i < 2; i++) {
        #pragma unroll
        for (int r = 0; r < 4; r++) {
            int R = wm * 32 + i * 16 + kg * 4 + r;   // C/D: col=lane&15, row=(lane>>4)*4+reg
            int gm = m0 + R;
            int bg = gm / L_;
            float sum = 0.f;
            #pragma unroll
            for (int j = 0; j < 8; j++) {
                int C = wn * 128 + j * 16 + lr;
                float x = acc[i][j][r] + bias2[bg * A_ + C];
                // fast tanh: 1 - 2/(e^{2x}+1)  (saturates correctly at +-inf)
                float ex = __expf(2.f * x);
                float th = 1.f - 2.f * __builtin_amdgcn_rcpf(ex + 1.f);
                sum += wf[C] * th;
            }
            #pragma unroll
            for (int mk = 1; mk < 16; mk <<= 1) sum += __shfl_xor(sum, mk);
            if (lr == 0) atomicAdd(&score_lds[R], sum);
        }
    }
    __syncthreads();
    if (tid < 64) scores[m0 + tid] = score_lds[tid];
}

// ---------------- kernel 2: mask + softmax over L ----------------------------
__global__ __launch_bounds__(256) void k_softmax(const float* __restrict__ scores,
                                                 const int* __restrict__ mask,
                                                 const float* __restrict__ bfp,
                                                 float* __restrict__ alpha) {
    int b = blockIdx.x, t = threadIdx.x;
    float bfv = bfp[0];
    float v = -INFINITY;
    if (t < L_) v = (mask[b * L_ + t] == 0) ? -1e9f : (scores[b * L_ + t] + bfv);
    __shared__ float redm[4], reds[4];
    float m = v;
    #pragma unroll
    for (int s = 1; s < 64; s <<= 1) m = fmaxf(m, __shfl_xor(m, s));
    int w = t >> 6;
    if ((t & 63) == 0) redm[w] = m;
    __syncthreads();
    m = fmaxf(fmaxf(redm[0], redm[1]), fmaxf(redm[2], redm[3]));
    float e = (t < L_) ? expf(v - m) : 0.f;
    float s = e;
    #pragma unroll
    for (int k = 1; k < 64; k <<= 1) s += __shfl_xor(s, k);
    if ((t & 63) == 0) reds[w] = s;
    __syncthreads();
    s = reds[0] + reds[1] + reds[2] + reds[3];
    if (t < L_) alpha[b * L_ + t] = e / s;
}

// ---------------- kernel 3: awe = sum_l alpha * enc --------------------------
// grid (8 e-chunks of 256, 256 batches), 256 threads = 4 groups x 64 lanes.
// Group g sums l in [g*49,(g+1)*49); cross-group reduce in LDS.
__global__ __launch_bounds__(256) void k_awe(const float* __restrict__ enc,
                                             const float* __restrict__ alpha,
                                             float* __restrict__ awe) {
    int b = blockIdx.y, ec = blockIdx.x, t = threadIdx.x;
    int g = t >> 6, lt = t & 63;
    __shared__ float al[L_];
    __shared__ float4 red[256];
    if (t < L_) al[t] = alpha[b * L_ + t];
    __syncthreads();
    int e0 = (ec << 8) + (lt << 2);
    const float* base = enc + (size_t)b * L_ * E_ + e0;
    float4 acc = {0.f, 0.f, 0.f, 0.f};
    int l0 = g * 49;
    #pragma unroll 7
    for (int l = l0; l < l0 + 49; l++) {
        float4 v = *reinterpret_cast<const float4*>(base + (size_t)l * E_);
        float a = al[l];
        acc.x += a * v.x; acc.y += a * v.y; acc.z += a * v.z; acc.w += a * v.w;
    }
    red[t] = acc;
    __syncthreads();
    if (t < 64) {
        float4 r0 = red[t], r1 = red[64 + t], r2 = red[128 + t], r3 = red[192 + t];
        float4 o;
        o.x = r0.x + r1.x + r2.x + r3.x;
        o.y = r0.y + r1.y + r2.y + r3.y;
        o.z = r0.z + r1.z + r2.z + r3.z;
        o.w = r0.w + r1.w + r2.w + r3.w;
        *reinterpret_cast<float4*>(awe + b * E_ + (ec << 8) + (t << 2)) = o;
    }
}

extern "C" void kernel_launch(void* const* d_in, const int* in_sizes, int n_in,
                              void* d_out, int out_size, void* d_ws, size_t ws_size,
                              hipStream_t stream) {
    const float* enc  = (const float*)d_in[0];
    const float* dec  = (const float*)d_in[1];
    const int*   mask = (const int*)d_in[2];
    const float* We   = (const float*)d_in[3];
    const float* be   = (const float*)d_in[4];
    const float* Wd   = (const float*)d_in[5];
    const float* bd   = (const float*)d_in[6];
    const float* wf   = (const float*)d_in[7];
    const float* bf   = (const float*)d_in[8];

    float* awe   = (float*)d_out;                  // [256][2048]
    float* alpha = awe + (size_t)B_ * E_;          // [256][196]

    char* ws = (char*)d_ws;
    unsigned short* WeP = (unsigned short*)ws;                       // 2 MB
    float* bias2  = (float*)(ws + (2u << 20));                       // 512 KB
    float* scores = (float*)(ws + (2u << 20) + (512u << 10));        // 200 KB

    hipLaunchKernelGGL(k_wepack, dim3((E_ * A_) / 256), dim3(256), 0, stream, We, WeP);
    hipLaunchKernelGGL(k_bias2, dim3(B_), dim3(256), 0, stream, dec, Wd, be, bd, bias2);
    hipLaunchKernelGGL(k_gemm_score, dim3(M_TOT / 64), dim3(512), 0, stream,
                       enc, WeP, bias2, wf, scores);
    hipLaunchKernelGGL(k_softmax, dim3(B_), dim3(256), 0, stream, scores, mask, bf, alpha);
    hipLaunchKernelGGL(k_awe, dim3(8, B_), dim3(256), 0, stream, enc, alpha, awe);
}

// Round 5
// 395.607 us; speedup vs baseline: 1.7262x; 1.2301x over previous
//
#include <hip/hip_runtime.h>
#include <hip/hip_bf16.h>

// Attention_50946902065218: Bahdanau-style attention
// B=256, L=196, E=2048, D=1024, A=512
// Pipeline:
//  k_wepack: We fp32 -> bf16, packed [kb][n][kg^swz(n)][e] (swizzle BAKED IN so
//            the linear global_load_lds copy lands bank-conflict-free)
//  k_bias2 : bias2[b][a] = be[a] + bd[a] + dec[b]@Wd[:,a]                (ws)
//  k_gemm_score (v5): 2-phase LDS dbuf MFMA GEMM with RAW s_barrier +
//     counted vmcnt(1) (A-prefetch stays in flight across barriers),
//     1x8 wave decomposition (wave tile 64x64) for VGPR<=64 -> 2 blocks/CU.
//  k_softmax: mask + softmax over L -> alpha (d_out part 2)
//  k_awe   : 4-way L-split reduction, 256-thread blocks

#define B_ 256
#define L_ 196
#define E_ 2048
#define D_ 1024
#define A_ 512
#define M_TOT (B_ * L_)   // 50176 = 784 * 64

typedef __attribute__((ext_vector_type(8))) short bf16x8;
typedef __attribute__((ext_vector_type(4))) float f32x4;

static __device__ __forceinline__ unsigned short f2bf(float f) {
    union { float f; unsigned u; } u{f};
    unsigned r = u.u + 0x7fffu + ((u.u >> 16) & 1u);   // RNE
    return (unsigned short)(r >> 16);
}

static __device__ __forceinline__ void gload_lds16(const void* g, void* l) {
    __builtin_amdgcn_global_load_lds(
        (const __attribute__((address_space(1))) unsigned int*)g,
        (__attribute__((address_space(3))) unsigned int*)l, 16, 0, 0);
}

// ---------------- kernel 0a: pack We (E x A fp32) -> WeP bf16 -----------------
// Element (k, n): kb=k>>5, kg=(k>>3)&3, e=k&7.
// Stored at kb*16384 + n*32 + (kg ^ ((n>>1)&3))*8 + e   (swizzled 16B slots)
__global__ __launch_bounds__(256) void k_wepack(const float* __restrict__ We,
                                                unsigned short* __restrict__ WeP) {
    int i = blockIdx.x * 256 + threadIdx.x;       // source index over 2048*512
    int k = i >> 9, n = i & 511;
    int kb = k >> 5, kg = (k >> 3) & 3, e = k & 7;
    int kgE = kg ^ ((n >> 1) & 3);
    WeP[(kb << 14) + (n << 5) + (kgE << 3) + e] = f2bf(We[i]);
}

// ---------------- kernel 0b: bias2 = be + bd + dec @ Wd ----------------------
__global__ __launch_bounds__(256) void k_bias2(const float* __restrict__ dec,
                                               const float* __restrict__ Wd,
                                               const float* __restrict__ be,
                                               const float* __restrict__ bd,
                                               float* __restrict__ bias2) {
    int b = blockIdx.x, t = threadIdx.x;
    __shared__ float ds[D_];
    for (int i = t; i < D_; i += 256) ds[i] = dec[b * D_ + i];
    __syncthreads();
    for (int a0 = 0; a0 < A_; a0 += 256) {
        int a = a0 + t;
        float acc = 0.f;
        #pragma unroll 8
        for (int d = 0; d < D_; d++) acc += ds[d] * Wd[d * A_ + a];
        bias2[b * A_ + a] = acc + be[a] + bd[a];
    }
}

// ---------------- kernel 1: fused GEMM + tanh + wf-dot -----------------------
// grid 784 blocks x 512 threads (8 waves, 1x8: wave owns 64 rows x 64 cols).
// Tile 64 rows x 512 cols, BK=32. Counted-wait double-buffered pipeline.
__global__ __launch_bounds__(512, 4) void k_gemm_score(
        const float* __restrict__ enc,
        const unsigned short* __restrict__ WeP,
        const float* __restrict__ bias2,
        const float* __restrict__ wf,
        float* __restrict__ scores) {
    __shared__ __align__(16) unsigned short aL[2][64 * 32];   // 4 KB each
    __shared__ __align__(16) unsigned short bL[2][512 * 32];  // 32 KB each
    __shared__ float score_lds[64];

    const int tid = threadIdx.x;
    const int m0 = blockIdx.x * 64;
    const int lane = tid & 63;
    const int wid = tid >> 6;
    const int kg = lane >> 4, lr = lane & 15;

    // A staging: thread -> row ar, 4 fp32 at col ak; swizzled 16B-slot dest
    const int ar = tid >> 3, ak = (tid & 7) << 2;
    const float* aSrc = enc + (size_t)(m0 + ar) * E_ + ak;
    const int aoff = ar * 32 + (ak ^ (((ar >> 1) & 3) << 3));

    // B staging: 4 x global_load_lds per wave, linear copy of 32KB K-slice
    // (source data pre-swizzled by k_wepack)
    const unsigned short* bSrcLane = WeP + (size_t)(wid * 512 + lane * 8);

    auto stageB = [&](int kb, int buf) {
        const unsigned short* s = bSrcLane + ((size_t)kb << 14);
        unsigned short* d = &bL[buf][wid * 512];
        #pragma unroll
        for (int i = 0; i < 4; i++)
            gload_lds16(s + i * 4096, d + i * 4096);
    };
    auto writeA = [&](const float4& v, int buf) {
        short4 p;
        p.x = (short)f2bf(v.x); p.y = (short)f2bf(v.y);
        p.z = (short)f2bf(v.z); p.w = (short)f2bf(v.w);
        *reinterpret_cast<short4*>(&aL[buf][aoff]) = p;
    };

    f32x4 acc[4][4];
    #pragma unroll
    for (int i = 0; i < 4; i++)
        #pragma unroll
        for (int j = 0; j < 4; j++) acc[i][j] = (f32x4){0.f, 0.f, 0.f, 0.f};

    auto computeTile = [&](int buf) {
        bf16x8 bfr[4];
        #pragma unroll
        for (int j = 0; j < 4; j++) {
            int n = wid * 64 + j * 16 + lr;
            bfr[j] = *reinterpret_cast<const bf16x8*>(
                &bL[buf][n * 32 + ((kg ^ ((n >> 1) & 3)) << 3)]);
        }
        #pragma unroll
        for (int i = 0; i < 4; i++) {
            int row = i * 16 + lr;
            bf16x8 af = *reinterpret_cast<const bf16x8*>(
                &aL[buf][row * 32 + ((kg ^ ((row >> 1) & 3)) << 3)]);
            #pragma unroll
            for (int j = 0; j < 4; j++)
                acc[i][j] = __builtin_amdgcn_mfma_f32_16x16x32_bf16(
                    af, bfr[j], acc[i][j], 0, 0, 0);
        }
    };

    // --- prologue: stage B(0); load A(0),A(1),A(2); write A(0) ---
    stageB(0, 0);
    __builtin_amdgcn_sched_barrier(0);     // pin: stageB vmem issues first
    float4 av0  = *reinterpret_cast<const float4*>(aSrc);
    float4 avH1 = *reinterpret_cast<const float4*>(aSrc + 32);
    float4 avH2 = *reinterpret_cast<const float4*>(aSrc + 64);
    writeA(av0, 0);                        // compiler auto-waits av0 (+stageB)
    asm volatile("s_waitcnt vmcnt(2) lgkmcnt(0)" ::: "memory");
    __builtin_amdgcn_s_barrier();
    __builtin_amdgcn_sched_barrier(0);

    int buf = 0;
    for (int t = 0; t < 63; t++) {
        stageB(t + 1, buf ^ 1);            // 4 vmem (oldest this step)
        __builtin_amdgcn_sched_barrier(0); // pin issue order: stageB < A-load
        int tn = (t + 3 > 63) ? 63 : t + 3;
        float4 avN = *reinterpret_cast<const float4*>(aSrc + tn * 32);
        __builtin_amdgcn_sched_barrier(0); // A-load is the newest vmem
        computeTile(buf);
        writeA(avH1, buf ^ 1);             // value forced-complete last barrier
        // wait stageB(t+1) (+1-step-old A), leave newest A-load in flight
        asm volatile("s_waitcnt vmcnt(1) lgkmcnt(0)" ::: "memory");
        __builtin_amdgcn_s_barrier();
        __builtin_amdgcn_sched_barrier(0);
        avH1 = avH2; avH2 = avN;
        buf ^= 1;
    }
    computeTile(buf);

    // --- epilogue: tanh + wf dot, reduce over cols ---
    if (tid < 64) score_lds[tid] = 0.f;
    __syncthreads();
    #pragma unroll
    for (int i = 0; i < 4; i++) {
        #pragma unroll
        for (int r = 0; r < 4; r++) {
            int R = i * 16 + kg * 4 + r;   // C/D: col=lane&15, row=(lane>>4)*4+reg
            int gm = m0 + R;
            int bg = gm / L_;
            float sum = 0.f;
            #pragma unroll
            for (int j = 0; j < 4; j++) {
                int C = wid * 64 + j * 16 + lr;
                float x = acc[i][j][r] + bias2[bg * A_ + C];
                // fast tanh: 1 - 2/(e^{2x}+1)  (saturates correctly at +-inf)
                float ex = __expf(2.f * x);
                float th = 1.f - 2.f * __builtin_amdgcn_rcpf(ex + 1.f);
                sum += wf[C] * th;
            }
            #pragma unroll
            for (int mk = 1; mk < 16; mk <<= 1) sum += __shfl_xor(sum, mk);
            if (lr == 0) atomicAdd(&score_lds[R], sum);
        }
    }
    __syncthreads();
    if (tid < 64) scores[m0 + tid] = score_lds[tid];
}

// ---------------- kernel 2: mask + softmax over L ----------------------------
__global__ __launch_bounds__(256) void k_softmax(const float* __restrict__ scores,
                                                 const int* __restrict__ mask,
                                                 const float* __restrict__ bfp,
                                                 float* __restrict__ alpha) {
    int b = blockIdx.x, t = threadIdx.x;
    float bfv = bfp[0];
    float v = -INFINITY;
    if (t < L_) v = (mask[b * L_ + t] == 0) ? -1e9f : (scores[b * L_ + t] + bfv);
    __shared__ float redm[4], reds[4];
    float m = v;
    #pragma unroll
    for (int s = 1; s < 64; s <<= 1) m = fmaxf(m, __shfl_xor(m, s));
    int w = t >> 6;
    if ((t & 63) == 0) redm[w] = m;
    __syncthreads();
    m = fmaxf(fmaxf(redm[0], redm[1]), fmaxf(redm[2], redm[3]));
    float e = (t < L_) ? expf(v - m) : 0.f;
    float s = e;
    #pragma unroll
    for (int k = 1; k < 64; k <<= 1) s += __shfl_xor(s, k);
    if ((t & 63) == 0) reds[w] = s;
    __syncthreads();
    s = reds[0] + reds[1] + reds[2] + reds[3];
    if (t < L_) alpha[b * L_ + t] = e / s;
}

// ---------------- kernel 3: awe = sum_l alpha * enc --------------------------
// grid (8 e-chunks of 256, 256 batches), 256 threads = 4 groups x 64 lanes.
// Group g sums l in [g*49,(g+1)*49); cross-group reduce in LDS.
__global__ __launch_bounds__(256) void k_awe(const float* __restrict__ enc,
                                             const float* __restrict__ alpha,
                                             float* __restrict__ awe) {
    int b = blockIdx.y, ec = blockIdx.x, t = threadIdx.x;
    int g = t >> 6, lt = t & 63;
    __shared__ float al[L_];
    __shared__ float4 red[256];
    if (t < L_) al[t] = alpha[b * L_ + t];
    __syncthreads();
    int e0 = (ec << 8) + (lt << 2);
    const float* base = enc + (size_t)b * L_ * E_ + e0;
    float4 acc = {0.f, 0.f, 0.f, 0.f};
    int l0 = g * 49;
    #pragma unroll 7
    for (int l = l0; l < l0 + 49; l++) {
        float4 v = *reinterpret_cast<const float4*>(base + (size_t)l * E_);
        float a = al[l];
        acc.x += a * v.x; acc.y += a * v.y; acc.z += a * v.z; acc.w += a * v.w;
    }
    red[t] = acc;
    __syncthreads();
    if (t < 64) {
        float4 r0 = red[t], r1 = red[64 + t], r2 = red[128 + t], r3 = red[192 + t];
        float4 o;
        o.x = r0.x + r1.x + r2.x + r3.x;
        o.y = r0.y + r1.y + r2.y + r3.y;
        o.z = r0.z + r1.z + r2.z + r3.z;
        o.w = r0.w + r1.w + r2.w + r3.w;
        *reinterpret_cast<float4*>(awe + b * E_ + (ec << 8) + (t << 2)) = o;
    }
}

extern "C" void kernel_launch(void* const* d_in, const int* in_sizes, int n_in,
                              void* d_out, int out_size, void* d_ws, size_t ws_size,
                              hipStream_t stream) {
    const float* enc  = (const float*)d_in[0];
    const float* dec  = (const float*)d_in[1];
    const int*   mask = (const int*)d_in[2];
    const float* We   = (const float*)d_in[3];
    const float* be   = (const float*)d_in[4];
    const float* Wd   = (const float*)d_in[5];
    const float* bd   = (const float*)d_in[6];
    const float* wf   = (const float*)d_in[7];
    const float* bf   = (const float*)d_in[8];

    float* awe   = (float*)d_out;                  // [256][2048]
    float* alpha = awe + (size_t)B_ * E_;          // [256][196]

    char* ws = (char*)d_ws;
    unsigned short* WeP = (unsigned short*)ws;                       // 2 MB
    float* bias2  = (float*)(ws + (2u << 20));                       // 512 KB
    float* scores = (float*)(ws + (2u << 20) + (512u << 10));        // 200 KB

    hipLaunchKernelGGL(k_wepack, dim3((E_ * A_) / 256), dim3(256), 0, stream, We, WeP);
    hipLaunchKernelGGL(k_bias2, dim3(B_), dim3(256), 0, stream, dec, Wd, be, bd, bias2);
    hipLaunchKernelGGL(k_gemm_score, dim3(M_TOT / 64), dim3(512), 0, stream,
                       enc, WeP, bias2, wf, scores);
    hipLaunchKernelGGL(k_softmax, dim3(B_), dim3(256), 0, stream, scores, mask, bf, alpha);
    hipLaunchKernelGGL(k_awe, dim3(8, B_), dim3(256), 0, stream, enc, alpha, awe);
}